// Round 7
// baseline (90.126 us; speedup 1.0000x reference)
//
#include <hip/hip_runtime.h>
#include <hip/hip_bf16.h>

#define KOFF 27
#define C 64
#define EPS 1e-5f
#define PER 8    // scan elems/lane: supports up to 512 blocks (nvox <= 131072)
#define RLW 26   // rowlist width (max sparse offsets per row)

typedef __attribute__((ext_vector_type(8))) short short8;
typedef __attribute__((ext_vector_type(4))) float f32x4;

__device__ inline unsigned short f2bf(float x) {
    __hip_bfloat16 h = __float2bfloat16(x);
    unsigned short u;
    __builtin_memcpy(&u, &h, 2);
    return u;
}

// ---- K1: fused prep. role-split by block range:
//  [0, nblk_b)           : per-block per-offset counts (no atomics)
//  [nblk_b, +nblk_f)     : feats fp32 -> bf16
//  [nblk_b+nblk_f, ...)  : W_conv/W_lin -> fragment-order bf16, zero-page
__launch_bounds__(256)
__global__ void prep(const float* __restrict__ feats, const int* __restrict__ nb,
                     const float* __restrict__ Wc, const float* __restrict__ Wl,
                     unsigned short* __restrict__ feats_bf, unsigned short* __restrict__ WcF,
                     unsigned short* __restrict__ WlF, unsigned short* __restrict__ Z,
                     int* __restrict__ cnt_blk, int nvox, int nblk_b, int nblk_f) {
    __shared__ int lds_nb[256 * KOFF];
    __shared__ int wcnt[KOFF][4];
    const int b = blockIdx.x;
    const int tid = threadIdx.x;

    if (b < nblk_b) {
        const int lane = tid & 63;
        const int wave = tid >> 6;
        const int row0 = b * 256;
        const long gb = (long)row0 * KOFF;
        const long glim = (long)nvox * KOFF;
        for (int j = tid; j < 256 * KOFF; j += 256) {
            long g = gb + j;
            lds_nb[j] = (g < glim) ? nb[g] : -1;
        }
        __syncthreads();
#pragma unroll
        for (int ko = 0; ko < KOFF; ++ko) {
            if (ko == 13) continue;
            int src = lds_nb[tid * KOFF + ko];
            unsigned long long msk = __ballot(src >= 0);
            if (lane == 0) wcnt[ko][wave] = __popcll(msk);
        }
        __syncthreads();
        if (tid < KOFF)
            cnt_blk[b * 32 + tid] =
                (tid == 13) ? 0 : (wcnt[tid][0] + wcnt[tid][1] + wcnt[tid][2] + wcnt[tid][3]);
    } else if (b < nblk_b + nblk_f) {
        const int n4 = nvox * 16;                 // nvox*64/4 float4 chunks
        const int stride = nblk_f * 256;
        for (int i = (b - nblk_b) * 256 + tid; i < n4; i += stride) {
            float4 v = ((const float4*)feats)[i];
            ushort4 u;
            u.x = f2bf(v.x); u.y = f2bf(v.y); u.z = f2bf(v.z); u.w = f2bf(v.w);
            ((ushort4*)feats_bf)[i] = u;
        }
    } else {
        const int NWc = KOFF * 4096;
        int i = (b - nblk_b - nblk_f) * 256 + tid;
        if (i < NWc + 4096) {
            int rem = i & 4095;
            int t = rem >> 10;
            int ks = (rem >> 9) & 1;
            int l = (rem >> 3) & 63;
            int j = i & 7;
            int c = ks * 32 + ((l >> 4) << 3) + j;
            int d = (t << 4) + (l & 15);
            if (i < NWc) {
                int ko = i >> 12;
                WcF[i] = f2bf(Wc[(ko << 12) + (c << 6) + d]);
            } else {
                WlF[rem] = f2bf(Wl[(c << 6) + d]);
            }
        } else if (i < NWc + 4096 + 128) {
            Z[i - NWc - 4096] = 0;
        }
    }
}

// ---- K2: exclusive scan over blocks, per offset (27 blocks x 1 wave) ----
__launch_bounds__(64)
__global__ void scan_pairs(const int* __restrict__ cnt_blk, int* __restrict__ blk_base,
                           int* __restrict__ tot, int nblk) {
    const int ko = blockIdx.x;
    const int lane = threadIdx.x;
    const int base = lane * PER;
    int loc[PER];
    int sum = 0;
#pragma unroll
    for (int i = 0; i < PER; ++i) {
        int idx = base + i;
        int v = (idx < nblk) ? cnt_blk[idx * 32 + ko] : 0;
        loc[i] = sum;
        sum += v;
    }
    int incl = sum;
#pragma unroll
    for (int d = 1; d < 64; d <<= 1) {
        int v = __shfl_up(incl, d, 64);
        if (lane >= d) incl += v;
    }
    int excl = incl - sum;
#pragma unroll
    for (int i = 0; i < PER; ++i) {
        int idx = base + i;
        if (idx < nblk) blk_base[idx * 32 + ko] = excl + loc[i];
    }
    if (lane == 63) tot[ko] = incl;
}

// ---- K3: write compacted pair srcs + per-row staged-index lists (no atomics) ----
__launch_bounds__(256)
__global__ void write_pairs(const int* __restrict__ nb, const int* __restrict__ blk_base,
                            const int* __restrict__ tot,
                            int* __restrict__ pairs, int* __restrict__ rowlist,
                            int* __restrict__ rowcnt, int nvox) {
    __shared__ int lds_nb[256 * KOFF];
    __shared__ int wcnt[KOFF][4];
    __shared__ int sb_l[KOFF];      // stage base per ko (16-padded prefix of tot)
    const int tid = threadIdx.x;
    const int lane = tid & 63;
    const int wave = tid >> 6;
    const int row0 = blockIdx.x * 256;
    {
        const long gb = (long)row0 * KOFF;
        const long glim = (long)nvox * KOFF;
        for (int j = tid; j < 256 * KOFF; j += 256) {
            long g = gb + j;
            lds_nb[j] = (g < glim) ? nb[g] : -1;
        }
    }
    __syncthreads();
#pragma unroll
    for (int ko = 0; ko < KOFF; ++ko) {
        if (ko == 13) continue;
        int src = lds_nb[tid * KOFF + ko];
        unsigned long long msk = __ballot(src >= 0);
        if (lane == 0) wcnt[ko][wave] = __popcll(msk);
    }
    if (wave == 0) {
        int v = 0;
        if (lane < KOFF) v = ((tot[lane] + 15) >> 4) << 4;   // tot[13]==0
        int incl = v;
#pragma unroll
        for (int d = 1; d < 32; d <<= 1) {
            int u = __shfl_up(incl, d, 64);
            if (lane >= d) incl += u;
        }
        if (lane < KOFF) sb_l[lane] = incl - v;
    }
    __syncthreads();

    const unsigned long long lmask = (1ull << lane) - 1;
    const int r = row0 + tid;
    int j = 0;
#pragma unroll
    for (int ko = 0; ko < KOFF; ++ko) {
        if (ko == 13) continue;
        int src = lds_nb[tid * KOFF + ko];
        unsigned long long msk = __ballot(src >= 0);
        int pre = __popcll(msk & lmask);
        int wb = 0;
#pragma unroll
        for (int w = 0; w < 4; ++w)
            if (w < wave) wb += wcnt[ko][w];
        if (src >= 0) {
            int pos = blk_base[blockIdx.x * 32 + ko] + wb + pre;
            pairs[(size_t)ko * nvox + pos] = src;
            rowlist[(size_t)r * RLW + j] = sb_l[ko] + pos;
            ++j;
        }
    }
    if (r < nvox) rowcnt[r] = j;
}

// ---- K4: sparse tiles -> streaming stores into stage (NO atomics) ----
__launch_bounds__(256)
__global__ void scatter_nc(const unsigned short* __restrict__ feats,
                           const unsigned short* __restrict__ WcF,
                           const unsigned short* __restrict__ zpage,
                           const int* __restrict__ tot,
                           const int* __restrict__ pairs,
                           float* __restrict__ stage, int nvox, int nwaves) {
    const int tid = threadIdx.x;
    const int lane = tid & 63;
    const int wave = tid >> 6;
    const int m = lane & 15;
    const int krow = lane >> 4;
    const int coff = krow * 8;
    const int gw = blockIdx.x * 4 + wave;

    int c = (lane < KOFF && lane != 13) ? tot[lane] : 0;
    int tiles = (c + 15) >> 4;
    int pre = tiles;
#pragma unroll
    for (int d = 1; d < 32; d <<= 1) {
        int v = __shfl_up(pre, d, 64);
        if (lane >= d) pre += v;
    }
    const int total = __shfl(pre, KOFF - 1, 64);
    const int base_l = pre - tiles;

    for (int t = gw; t < total; t += nwaves) {
        unsigned long long msk = __ballot(lane < KOFF && base_l <= t && t < pre);
        int ko = __ffsll(msk) - 1;
        int base = __shfl(base_l, ko, 64);
        int cko = __shfl(c, ko, 64);
        int s0 = (t - base) * 16;

        int slot = s0 + m;
        int src = (slot < cko) ? pairs[(size_t)ko * nvox + slot] : -1;
        const unsigned short* pa = (src >= 0) ? feats + ((size_t)src << 6) : zpage;
        short8 a0 = *(const short8*)(pa + coff);
        short8 a1 = *(const short8*)(pa + 32 + coff);

        const unsigned short* w = WcF + ((size_t)ko << 12) + lane * 8;
        f32x4 c4[4];
#pragma unroll
        for (int t4 = 0; t4 < 4; ++t4) {
            short8 b0 = *(const short8*)(w + t4 * 1024);
            short8 b1 = *(const short8*)(w + t4 * 1024 + 512);
            c4[t4] = (f32x4){0.f, 0.f, 0.f, 0.f};
            c4[t4] = __builtin_amdgcn_mfma_f32_16x16x32_bf16(a0, b0, c4[t4], 0, 0, 0);
            c4[t4] = __builtin_amdgcn_mfma_f32_16x16x32_bf16(a1, b1, c4[t4], 0, 0, 0);
        }

        const int srow = base * 16 + s0;   // staged row base for this tile
#pragma unroll
        for (int t4 = 0; t4 < 4; ++t4)
#pragma unroll
            for (int i = 0; i < 4; ++i) {
                int row16 = krow * 4 + i;
                if (s0 + row16 < cko)
                    stage[(size_t)(srow + row16) * 64 + t4 * 16 + m] = c4[t4][i];
            }
    }
}

// ---- K5: fused tail: W13 GEMM + gather-reduce contributions + linear + LN ----
__launch_bounds__(256)
__global__ void fused_tail(const unsigned short* __restrict__ feats,
                           const unsigned short* __restrict__ WcF,
                           const unsigned short* __restrict__ WlF,
                           const float* __restrict__ stage,
                           const int* __restrict__ rowcnt,
                           const int* __restrict__ rowlist,
                           const float* __restrict__ b_conv,
                           const float* __restrict__ b_lin,
                           const float* __restrict__ gamma,
                           const float* __restrict__ beta,
                           float* __restrict__ out, int nvox) {
    __shared__ unsigned short xl[4][32][72];   // per-wave x tile, padded pitch
    const int tid = threadIdx.x;
    const int lane = tid & 63;
    const int wave = tid >> 6;
    const int m = lane & 15;
    const int krow = lane >> 4;
    const int coff = krow * 8;

    const int rb = blockIdx.x * 128 + wave * 32 + m;
    const int r0 = min(rb, nvox - 1);
    const int r1 = min(rb + 16, nvox - 1);

    short8 a00 = *(const short8*)(feats + (size_t)r0 * C + coff);
    short8 a01 = *(const short8*)(feats + (size_t)r0 * C + 32 + coff);
    short8 a10 = *(const short8*)(feats + (size_t)r1 * C + coff);
    short8 a11 = *(const short8*)(feats + (size_t)r1 * C + 32 + coff);

    const unsigned short* w13 = WcF + 13 * 4096 + lane * 8;
    f32x4 c0[4], c1[4];
#pragma unroll
    for (int t = 0; t < 4; ++t) {
        c0[t] = (f32x4){0.f, 0.f, 0.f, 0.f};
        c1[t] = (f32x4){0.f, 0.f, 0.f, 0.f};
    }
#pragma unroll
    for (int t = 0; t < 4; ++t) {
        short8 b0 = *(const short8*)(w13 + t * 1024);
        short8 b1 = *(const short8*)(w13 + t * 1024 + 512);
        c0[t] = __builtin_amdgcn_mfma_f32_16x16x32_bf16(a00, b0, c0[t], 0, 0, 0);
        c0[t] = __builtin_amdgcn_mfma_f32_16x16x32_bf16(a01, b1, c0[t], 0, 0, 0);
        c1[t] = __builtin_amdgcn_mfma_f32_16x16x32_bf16(a10, b0, c1[t], 0, 0, 0);
        c1[t] = __builtin_amdgcn_mfma_f32_16x16x32_bf16(a11, b1, c1[t], 0, 0, 0);
    }

    // gather sparse contributions (coalesced 64B reads, ~2.25 per row)
#pragma unroll
    for (int rbk = 0; rbk < 2; ++rbk) {
        f32x4* cc = rbk ? c1 : c0;
#pragma unroll
        for (int i = 0; i < 4; ++i) {
            int rr = blockIdx.x * 128 + wave * 32 + rbk * 16 + krow * 4 + i;
            int ncon = (rr < nvox) ? rowcnt[rr] : 0;
            const int* rl = rowlist + (size_t)rr * RLW;
            for (int jj = 0; jj < ncon; ++jj) {
                int sr = rl[jj];
                const float* sp = stage + (size_t)sr * 64 + m;
                cc[0][i] += sp[0];
                cc[1][i] += sp[16];
                cc[2][i] += sp[32];
                cc[3][i] += sp[48];
            }
        }
    }

    float bc[4];
#pragma unroll
    for (int t = 0; t < 4; ++t) bc[t] = b_conv[t * 16 + m];

    // x -> bf16 LDS tile (transpose C-layout -> A-layout for the linear MFMA)
#pragma unroll
    for (int rbk = 0; rbk < 2; ++rbk) {
        f32x4* cc = rbk ? c1 : c0;
#pragma unroll
        for (int t = 0; t < 4; ++t)
#pragma unroll
            for (int i = 0; i < 4; ++i)
                xl[wave][rbk * 16 + krow * 4 + i][t * 16 + m] = f2bf(cc[t][i] + bc[t]);
    }
    __syncthreads();

    short8 xa00 = *(const short8*)(&xl[wave][m][coff]);
    short8 xa01 = *(const short8*)(&xl[wave][m][32 + coff]);
    short8 xa10 = *(const short8*)(&xl[wave][m + 16][coff]);
    short8 xa11 = *(const short8*)(&xl[wave][m + 16][32 + coff]);

    f32x4 d0[4], d1[4];
#pragma unroll
    for (int t = 0; t < 4; ++t) {
        d0[t] = (f32x4){0.f, 0.f, 0.f, 0.f};
        d1[t] = (f32x4){0.f, 0.f, 0.f, 0.f};
    }
    const unsigned short* wl = WlF + lane * 8;
#pragma unroll
    for (int t = 0; t < 4; ++t) {
        short8 wb0 = *(const short8*)(wl + t * 1024);
        short8 wb1 = *(const short8*)(wl + t * 1024 + 512);
        d0[t] = __builtin_amdgcn_mfma_f32_16x16x32_bf16(xa00, wb0, d0[t], 0, 0, 0);
        d0[t] = __builtin_amdgcn_mfma_f32_16x16x32_bf16(xa01, wb1, d0[t], 0, 0, 0);
        d1[t] = __builtin_amdgcn_mfma_f32_16x16x32_bf16(xa10, wb0, d1[t], 0, 0, 0);
        d1[t] = __builtin_amdgcn_mfma_f32_16x16x32_bf16(xa11, wb1, d1[t], 0, 0, 0);
    }

    float bl[4], g4[4], bt[4];
#pragma unroll
    for (int t = 0; t < 4; ++t) {
        int col = t * 16 + m;
        bl[t] = b_lin[col];
        g4[t] = gamma[col];
        bt[t] = beta[col];
    }

#pragma unroll
    for (int rbk = 0; rbk < 2; ++rbk) {
        f32x4* d = rbk ? d1 : d0;
        float s1[4], s2[4];
#pragma unroll
        for (int i = 0; i < 4; ++i) {
            float a0 = d[0][i] + bl[0];
            float a1 = d[1][i] + bl[1];
            float a2 = d[2][i] + bl[2];
            float a3 = d[3][i] + bl[3];
            d[0][i] = a0; d[1][i] = a1; d[2][i] = a2; d[3][i] = a3;
            s1[i] = a0 + a1 + a2 + a3;
            s2[i] = a0 * a0 + a1 * a1 + a2 * a2 + a3 * a3;
        }
#pragma unroll
        for (int msk = 1; msk < 16; msk <<= 1) {
#pragma unroll
            for (int i = 0; i < 4; ++i) {
                s1[i] += __shfl_xor(s1[i], msk, 64);
                s2[i] += __shfl_xor(s2[i], msk, 64);
            }
        }
#pragma unroll
        for (int i = 0; i < 4; ++i) {
            float mu = s1[i] * (1.f / 64.f);
            float var = s2[i] * (1.f / 64.f) - mu * mu;
            float rs = rsqrtf(var + EPS);
            int grow = blockIdx.x * 128 + wave * 32 + rbk * 16 + krow * 4 + i;
            if (grow < nvox) {
#pragma unroll
                for (int t = 0; t < 4; ++t)
                    out[(size_t)grow * C + t * 16 + m] = g4[t] * (d[t][i] - mu) * rs + bt[t];
            }
        }
    }
}

extern "C" void kernel_launch(void* const* d_in, const int* in_sizes, int n_in,
                              void* d_out, int out_size, void* d_ws, size_t ws_size,
                              hipStream_t stream) {
    const float* feats = (const float*)d_in[0];
    const int* nb = (const int*)d_in[1];
    const float* Wc = (const float*)d_in[2];
    const float* b_conv = (const float*)d_in[3];
    const float* Wl = (const float*)d_in[4];
    const float* b_lin = (const float*)d_in[5];
    const float* gamma = (const float*)d_in[6];
    const float* beta = (const float*)d_in[7];
    float* out = (float*)d_out;

    const int nvox = in_sizes[0] / C;
    const int nblk_b = (nvox + 255) / 256;

    // ws layout
    char* ws = (char*)d_ws;
    unsigned short* feats_bf = (unsigned short*)ws;
    size_t off = (size_t)nvox * C * 2;
    unsigned short* WcF = (unsigned short*)(ws + off); off += KOFF * 4096 * 2;
    unsigned short* WlF = (unsigned short*)(ws + off); off += 4096 * 2;
    unsigned short* Z = (unsigned short*)(ws + off);   off += 256;
    off = (off + 255) & ~(size_t)255;
    int* cnt_blk = (int*)(ws + off);                    off += (size_t)nblk_b * 32 * 4;
    off = (off + 255) & ~(size_t)255;
    int* blk_base = (int*)(ws + off);                   off += (size_t)nblk_b * 32 * 4;
    off = (off + 255) & ~(size_t)255;
    int* tot = (int*)(ws + off);                        off += 256;
    off = (off + 255) & ~(size_t)255;
    int* pairs = (int*)(ws + off);                      off += (size_t)nvox * KOFF * 4;
    off = (off + 255) & ~(size_t)255;
    int* rowcnt = (int*)(ws + off);                     off += (size_t)nvox * 4;
    off = (off + 255) & ~(size_t)255;
    int* rowlist = (int*)(ws + off);                    off += (size_t)nvox * RLW * 4;
    off = (off + 255) & ~(size_t)255;
    float* stage = (float*)(ws + off);

    const int NBF = 1024;                              // cvt_feats blocks
    const int NBW = (KOFF * 4096 + 4096 + 128 + 255) / 256;
    prep<<<nblk_b + NBF + NBW, 256, 0, stream>>>(feats, nb, Wc, Wl, feats_bf, WcF, WlF, Z,
                                                 cnt_blk, nvox, nblk_b, NBF);

    scan_pairs<<<KOFF, 64, 0, stream>>>(cnt_blk, blk_base, tot, nblk_b);

    write_pairs<<<nblk_b, 256, 0, stream>>>(nb, blk_base, tot, pairs, rowlist, rowcnt, nvox);

    const int NB4 = 2048;
    scatter_nc<<<NB4, 256, 0, stream>>>(feats_bf, WcF, Z, tot, pairs, stage, nvox, NB4 * 4);

    int nblk = (nvox + 127) / 128;
    fused_tail<<<nblk, 256, 0, stream>>>(feats_bf, WcF, WlF, stage, rowcnt, rowlist,
                                         b_conv, b_lin, gamma, beta, out, nvox);
}

// Round 8
// 65.512 us; speedup vs baseline: 1.3757x; 1.3757x over previous
//
#include <hip/hip_runtime.h>
#include <hip/hip_bf16.h>

#define KOFF 27
#define C 64
#define EPS 1e-5f
#define PER 8    // scan elems/lane: supports up to 512 blocks (nvox <= 131072)
#define RLW 28   // rowlist width (26 max contribs, padded for int4 alignment)
#define CL 4     // unrolled contribution loads per row

typedef __attribute__((ext_vector_type(8))) short short8;
typedef __attribute__((ext_vector_type(4))) float f32x4;

__device__ inline unsigned short f2bf(float x) {
    __hip_bfloat16 h = __float2bfloat16(x);
    unsigned short u;
    __builtin_memcpy(&u, &h, 2);
    return u;
}

// ---- K1: fused prep. role-split by block range:
//  [0, nblk_b)           : per-block per-offset counts (no atomics)
//  [nblk_b, +nblk_f)     : feats fp32 -> bf16
//  [nblk_b+nblk_f, ...)  : W_conv/W_lin -> fragment-order bf16, zero-page
__launch_bounds__(256)
__global__ void prep(const float* __restrict__ feats, const int* __restrict__ nb,
                     const float* __restrict__ Wc, const float* __restrict__ Wl,
                     unsigned short* __restrict__ feats_bf, unsigned short* __restrict__ WcF,
                     unsigned short* __restrict__ WlF, unsigned short* __restrict__ Z,
                     int* __restrict__ cnt_blk, int nvox, int nblk_b, int nblk_f) {
    __shared__ int lds_nb[256 * KOFF];
    __shared__ int wcnt[KOFF][4];
    const int b = blockIdx.x;
    const int tid = threadIdx.x;

    if (b < nblk_b) {
        const int lane = tid & 63;
        const int wave = tid >> 6;
        const int row0 = b * 256;
        const long gb = (long)row0 * KOFF;
        const long glim = (long)nvox * KOFF;
        for (int j = tid; j < 256 * KOFF; j += 256) {
            long g = gb + j;
            lds_nb[j] = (g < glim) ? nb[g] : -1;
        }
        __syncthreads();
#pragma unroll
        for (int ko = 0; ko < KOFF; ++ko) {
            if (ko == 13) continue;
            int src = lds_nb[tid * KOFF + ko];
            unsigned long long msk = __ballot(src >= 0);
            if (lane == 0) wcnt[ko][wave] = __popcll(msk);
        }
        __syncthreads();
        if (tid < KOFF)
            cnt_blk[b * 32 + tid] =
                (tid == 13) ? 0 : (wcnt[tid][0] + wcnt[tid][1] + wcnt[tid][2] + wcnt[tid][3]);
    } else if (b < nblk_b + nblk_f) {
        const int n4 = nvox * 16;                 // nvox*64/4 float4 chunks
        const int stride = nblk_f * 256;
        for (int i = (b - nblk_b) * 256 + tid; i < n4; i += stride) {
            float4 v = ((const float4*)feats)[i];
            ushort4 u;
            u.x = f2bf(v.x); u.y = f2bf(v.y); u.z = f2bf(v.z); u.w = f2bf(v.w);
            ((ushort4*)feats_bf)[i] = u;
        }
    } else {
        const int NWc = KOFF * 4096;
        int i = (b - nblk_b - nblk_f) * 256 + tid;
        if (i < NWc + 4096) {
            int rem = i & 4095;
            int t = rem >> 10;
            int ks = (rem >> 9) & 1;
            int l = (rem >> 3) & 63;
            int j = i & 7;
            int c = ks * 32 + ((l >> 4) << 3) + j;
            int d = (t << 4) + (l & 15);
            if (i < NWc) {
                int ko = i >> 12;
                WcF[i] = f2bf(Wc[(ko << 12) + (c << 6) + d]);
            } else {
                WlF[rem] = f2bf(Wl[(c << 6) + d]);
            }
        } else if (i < NWc + 4096 + 128) {
            Z[i - NWc - 4096] = 0;
        }
    }
}

// ---- K2: exclusive scan over blocks, per offset (27 blocks x 1 wave) ----
__launch_bounds__(64)
__global__ void scan_pairs(const int* __restrict__ cnt_blk, int* __restrict__ blk_base,
                           int* __restrict__ tot, int nblk) {
    const int ko = blockIdx.x;
    const int lane = threadIdx.x;
    const int base = lane * PER;
    int loc[PER];
    int sum = 0;
#pragma unroll
    for (int i = 0; i < PER; ++i) {
        int idx = base + i;
        int v = (idx < nblk) ? cnt_blk[idx * 32 + ko] : 0;
        loc[i] = sum;
        sum += v;
    }
    int incl = sum;
#pragma unroll
    for (int d = 1; d < 64; d <<= 1) {
        int v = __shfl_up(incl, d, 64);
        if (lane >= d) incl += v;
    }
    int excl = incl - sum;
#pragma unroll
    for (int i = 0; i < PER; ++i) {
        int idx = base + i;
        if (idx < nblk) blk_base[idx * 32 + ko] = excl + loc[i];
    }
    if (lane == 63) tot[ko] = incl;
}

// ---- K3: write compacted pair srcs + per-row staged-index lists (no atomics) ----
__launch_bounds__(256)
__global__ void write_pairs(const int* __restrict__ nb, const int* __restrict__ blk_base,
                            const int* __restrict__ tot,
                            int* __restrict__ pairs, int* __restrict__ rowlist,
                            int* __restrict__ rowcnt, int nvox) {
    __shared__ int lds_nb[256 * KOFF];
    __shared__ int wcnt[KOFF][4];
    __shared__ int sb_l[KOFF];      // stage base per ko (16-padded prefix of tot)
    const int tid = threadIdx.x;
    const int lane = tid & 63;
    const int wave = tid >> 6;
    const int row0 = blockIdx.x * 256;
    {
        const long gb = (long)row0 * KOFF;
        const long glim = (long)nvox * KOFF;
        for (int j = tid; j < 256 * KOFF; j += 256) {
            long g = gb + j;
            lds_nb[j] = (g < glim) ? nb[g] : -1;
        }
    }
    __syncthreads();
#pragma unroll
    for (int ko = 0; ko < KOFF; ++ko) {
        if (ko == 13) continue;
        int src = lds_nb[tid * KOFF + ko];
        unsigned long long msk = __ballot(src >= 0);
        if (lane == 0) wcnt[ko][wave] = __popcll(msk);
    }
    if (wave == 0) {
        int v = 0;
        if (lane < KOFF) v = ((tot[lane] + 15) >> 4) << 4;   // tot[13]==0
        int incl = v;
#pragma unroll
        for (int d = 1; d < 32; d <<= 1) {
            int u = __shfl_up(incl, d, 64);
            if (lane >= d) incl += u;
        }
        if (lane < KOFF) sb_l[lane] = incl - v;
    }
    __syncthreads();

    const unsigned long long lmask = (1ull << lane) - 1;
    const int r = row0 + tid;
    int j = 0;
#pragma unroll
    for (int ko = 0; ko < KOFF; ++ko) {
        if (ko == 13) continue;
        int src = lds_nb[tid * KOFF + ko];
        unsigned long long msk = __ballot(src >= 0);
        int pre = __popcll(msk & lmask);
        int wb = 0;
#pragma unroll
        for (int w = 0; w < 4; ++w)
            if (w < wave) wb += wcnt[ko][w];
        if (src >= 0) {
            int pos = blk_base[blockIdx.x * 32 + ko] + wb + pre;
            pairs[(size_t)ko * nvox + pos] = src;
            rowlist[(size_t)r * RLW + j] = sb_l[ko] + pos;
            ++j;
        }
    }
    if (r < nvox) rowcnt[r] = j;
}

// ---- K4: sparse tiles -> streaming float4 stores into stage (NO atomics) ----
// stage element layout per row: [m*4 + t] holds channel t*16+m
__launch_bounds__(256)
__global__ void scatter_nc(const unsigned short* __restrict__ feats,
                           const unsigned short* __restrict__ WcF,
                           const unsigned short* __restrict__ zpage,
                           const int* __restrict__ tot,
                           const int* __restrict__ pairs,
                           float* __restrict__ stage, int nvox, int nwaves) {
    const int tid = threadIdx.x;
    const int lane = tid & 63;
    const int wave = tid >> 6;
    const int m = lane & 15;
    const int krow = lane >> 4;
    const int coff = krow * 8;
    const int gw = blockIdx.x * 4 + wave;

    int c = (lane < KOFF && lane != 13) ? tot[lane] : 0;
    int tiles = (c + 15) >> 4;
    int pre = tiles;
#pragma unroll
    for (int d = 1; d < 32; d <<= 1) {
        int v = __shfl_up(pre, d, 64);
        if (lane >= d) pre += v;
    }
    const int total = __shfl(pre, KOFF - 1, 64);
    const int base_l = pre - tiles;

    for (int t = gw; t < total; t += nwaves) {
        unsigned long long msk = __ballot(lane < KOFF && base_l <= t && t < pre);
        int ko = __ffsll(msk) - 1;
        int base = __shfl(base_l, ko, 64);
        int cko = __shfl(c, ko, 64);
        int s0 = (t - base) * 16;

        int slot = s0 + m;
        int src = (slot < cko) ? pairs[(size_t)ko * nvox + slot] : -1;
        const unsigned short* pa = (src >= 0) ? feats + ((size_t)src << 6) : zpage;
        short8 a0 = *(const short8*)(pa + coff);
        short8 a1 = *(const short8*)(pa + 32 + coff);

        const unsigned short* w = WcF + ((size_t)ko << 12) + lane * 8;
        f32x4 c4[4];
#pragma unroll
        for (int t4 = 0; t4 < 4; ++t4) {
            short8 b0 = *(const short8*)(w + t4 * 1024);
            short8 b1 = *(const short8*)(w + t4 * 1024 + 512);
            c4[t4] = (f32x4){0.f, 0.f, 0.f, 0.f};
            c4[t4] = __builtin_amdgcn_mfma_f32_16x16x32_bf16(a0, b0, c4[t4], 0, 0, 0);
            c4[t4] = __builtin_amdgcn_mfma_f32_16x16x32_bf16(a1, b1, c4[t4], 0, 0, 0);
        }

        const int srow = base * 16 + s0;   // staged row base for this tile
#pragma unroll
        for (int i = 0; i < 4; ++i) {
            int row16 = krow * 4 + i;
            if (s0 + row16 < cko) {
                float4 st = make_float4(c4[0][i], c4[1][i], c4[2][i], c4[3][i]);
                *(float4*)(stage + (size_t)(srow + row16) * 64 + m * 4) = st;
            }
        }
    }
}

// ---- K5: fused tail (16 rows/wave): W13 GEMM + gather-reduce + linear + LN ----
__launch_bounds__(256)
__global__ void fused_tail(const unsigned short* __restrict__ feats,
                           const unsigned short* __restrict__ WcF,
                           const unsigned short* __restrict__ WlF,
                           const float* __restrict__ stage,
                           const int* __restrict__ rowcnt,
                           const int* __restrict__ rowlist,
                           const float* __restrict__ zrow,
                           const float* __restrict__ b_conv,
                           const float* __restrict__ b_lin,
                           const float* __restrict__ gamma,
                           const float* __restrict__ beta,
                           float* __restrict__ out, int nvox) {
    __shared__ unsigned short xl[4][16][72];   // per-wave x tile, padded pitch
    const int tid = threadIdx.x;
    const int lane = tid & 63;
    const int wave = tid >> 6;
    const int m = lane & 15;
    const int krow = lane >> 4;
    const int coff = krow * 8;
    const int rb = (blockIdx.x * 4 + wave) * 16;

    // --- gather metadata early (independent of the MFMAs below) ---
    int ncon[4];
    int4 rl4[4];
#pragma unroll
    for (int i = 0; i < 4; ++i) {
        int rr = rb + krow * 4 + i;
        bool ok = (rr < nvox);
        int rs = ok ? rr : 0;
        ncon[i] = ok ? rowcnt[rs] : 0;
        rl4[i] = *(const int4*)(rowlist + (size_t)rs * RLW);
    }

    // --- W13 self GEMM ---
    const int r0 = min(rb + m, nvox - 1);
    short8 a00 = *(const short8*)(feats + (size_t)r0 * C + coff);
    short8 a01 = *(const short8*)(feats + (size_t)r0 * C + 32 + coff);
    const unsigned short* w13 = WcF + 13 * 4096 + lane * 8;
    f32x4 cc[4];
#pragma unroll
    for (int t = 0; t < 4; ++t) {
        short8 b0 = *(const short8*)(w13 + t * 1024);
        short8 b1 = *(const short8*)(w13 + t * 1024 + 512);
        cc[t] = (f32x4){0.f, 0.f, 0.f, 0.f};
        cc[t] = __builtin_amdgcn_mfma_f32_16x16x32_bf16(a00, b0, cc[t], 0, 0, 0);
        cc[t] = __builtin_amdgcn_mfma_f32_16x16x32_bf16(a01, b1, cc[t], 0, 0, 0);
    }

    // --- gather contributions: one coalesced float4 per contrib, predicated ---
#pragma unroll
    for (int i = 0; i < 4; ++i) {
        const int* rlp = (const int*)&rl4[i];
#pragma unroll
        for (int jj = 0; jj < CL; ++jj) {
            const float* sp = (jj < ncon[i])
                                  ? stage + (size_t)rlp[jj] * 64 + m * 4
                                  : zrow + m * 4;
            float4 v = *(const float4*)sp;
            cc[0][i] += v.x; cc[1][i] += v.y; cc[2][i] += v.z; cc[3][i] += v.w;
        }
        if (ncon[i] > CL) {   // rare (~1% of rows)
            int rr = rb + krow * 4 + i;
            for (int jj = CL; jj < ncon[i]; ++jj) {
                int sr = rowlist[(size_t)rr * RLW + jj];
                float4 v = *(const float4*)(stage + (size_t)sr * 64 + m * 4);
                cc[0][i] += v.x; cc[1][i] += v.y; cc[2][i] += v.z; cc[3][i] += v.w;
            }
        }
    }

    // --- +b_conv, bf16 round-trip through per-wave LDS tile ---
    float bc[4];
#pragma unroll
    for (int t = 0; t < 4; ++t) bc[t] = b_conv[t * 16 + m];
#pragma unroll
    for (int t = 0; t < 4; ++t)
#pragma unroll
        for (int i = 0; i < 4; ++i)
            xl[wave][krow * 4 + i][t * 16 + m] = f2bf(cc[t][i] + bc[t]);
    __syncthreads();

    short8 xa0 = *(const short8*)(&xl[wave][m][coff]);
    short8 xa1 = *(const short8*)(&xl[wave][m][32 + coff]);

    f32x4 d[4];
#pragma unroll
    for (int t = 0; t < 4; ++t) d[t] = (f32x4){0.f, 0.f, 0.f, 0.f};
    const unsigned short* wl = WlF + lane * 8;
#pragma unroll
    for (int t = 0; t < 4; ++t) {
        short8 wb0 = *(const short8*)(wl + t * 1024);
        short8 wb1 = *(const short8*)(wl + t * 1024 + 512);
        d[t] = __builtin_amdgcn_mfma_f32_16x16x32_bf16(xa0, wb0, d[t], 0, 0, 0);
        d[t] = __builtin_amdgcn_mfma_f32_16x16x32_bf16(xa1, wb1, d[t], 0, 0, 0);
    }

    float bl[4], g4[4], bt[4];
#pragma unroll
    for (int t = 0; t < 4; ++t) {
        int col = t * 16 + m;
        bl[t] = b_lin[col];
        g4[t] = gamma[col];
        bt[t] = beta[col];
    }

    float s1[4], s2[4];
#pragma unroll
    for (int i = 0; i < 4; ++i) {
        float a0 = d[0][i] + bl[0];
        float a1 = d[1][i] + bl[1];
        float a2 = d[2][i] + bl[2];
        float a3 = d[3][i] + bl[3];
        d[0][i] = a0; d[1][i] = a1; d[2][i] = a2; d[3][i] = a3;
        s1[i] = a0 + a1 + a2 + a3;
        s2[i] = a0 * a0 + a1 * a1 + a2 * a2 + a3 * a3;
    }
#pragma unroll
    for (int msk = 1; msk < 16; msk <<= 1) {
#pragma unroll
        for (int i = 0; i < 4; ++i) {
            s1[i] += __shfl_xor(s1[i], msk, 64);
            s2[i] += __shfl_xor(s2[i], msk, 64);
        }
    }
#pragma unroll
    for (int i = 0; i < 4; ++i) {
        float mu = s1[i] * (1.f / 64.f);
        float var = s2[i] * (1.f / 64.f) - mu * mu;
        float rs = rsqrtf(var + EPS);
        int grow = rb + krow * 4 + i;
        if (grow < nvox) {
#pragma unroll
            for (int t = 0; t < 4; ++t)
                out[(size_t)grow * C + t * 16 + m] = g4[t] * (d[t][i] - mu) * rs + bt[t];
        }
    }
}

extern "C" void kernel_launch(void* const* d_in, const int* in_sizes, int n_in,
                              void* d_out, int out_size, void* d_ws, size_t ws_size,
                              hipStream_t stream) {
    const float* feats = (const float*)d_in[0];
    const int* nb = (const int*)d_in[1];
    const float* Wc = (const float*)d_in[2];
    const float* b_conv = (const float*)d_in[3];
    const float* Wl = (const float*)d_in[4];
    const float* b_lin = (const float*)d_in[5];
    const float* gamma = (const float*)d_in[6];
    const float* beta = (const float*)d_in[7];
    float* out = (float*)d_out;

    const int nvox = in_sizes[0] / C;
    const int nblk_b = (nvox + 255) / 256;

    // ws layout
    char* ws = (char*)d_ws;
    unsigned short* feats_bf = (unsigned short*)ws;
    size_t off = (size_t)nvox * C * 2;
    unsigned short* WcF = (unsigned short*)(ws + off); off += KOFF * 4096 * 2;
    unsigned short* WlF = (unsigned short*)(ws + off); off += 4096 * 2;
    unsigned short* Z = (unsigned short*)(ws + off);   off += 256;
    off = (off + 255) & ~(size_t)255;
    int* cnt_blk = (int*)(ws + off);                    off += (size_t)nblk_b * 32 * 4;
    off = (off + 255) & ~(size_t)255;
    int* blk_base = (int*)(ws + off);                   off += (size_t)nblk_b * 32 * 4;
    off = (off + 255) & ~(size_t)255;
    int* tot = (int*)(ws + off);                        off += 256;
    off = (off + 255) & ~(size_t)255;
    int* pairs = (int*)(ws + off);                      off += (size_t)nvox * KOFF * 4;
    off = (off + 255) & ~(size_t)255;
    int* rowcnt = (int*)(ws + off);                     off += (size_t)nvox * 4;
    off = (off + 255) & ~(size_t)255;
    int* rowlist = (int*)(ws + off);                    off += (size_t)nvox * RLW * 4;
    off = (off + 255) & ~(size_t)255;
    float* stage = (float*)(ws + off);

    const int NBF = 1024;                              // cvt_feats blocks
    const int NBW = (KOFF * 4096 + 4096 + 128 + 255) / 256;
    prep<<<nblk_b + NBF + NBW, 256, 0, stream>>>(feats, nb, Wc, Wl, feats_bf, WcF, WlF, Z,
                                                 cnt_blk, nvox, nblk_b, NBF);

    scan_pairs<<<KOFF, 64, 0, stream>>>(cnt_blk, blk_base, tot, nblk_b);

    write_pairs<<<nblk_b, 256, 0, stream>>>(nb, blk_base, tot, pairs, rowlist, rowcnt, nvox);

    const int NB4 = 2048;
    scatter_nc<<<NB4, 256, 0, stream>>>(feats_bf, WcF, Z, tot, pairs, stage, nvox, NB4 * 4);

    int nblk_t = (nvox + 63) / 64;
    fused_tail<<<nblk_t, 256, 0, stream>>>(feats_bf, WcF, WlF, stage, rowcnt, rowlist,
                                           (const float*)Z, b_conv, b_lin, gamma, beta,
                                           out, nvox);
}